// Round 1
// baseline (399.563 us; speedup 1.0000x reference)
//
#include <hip/hip_runtime.h>
#include <hip/hip_bf16.h>
#include <stdint.h>

#define D_MODEL 1024
#define NHEAD 16
#define SEQ 2048
#define BATCH 4
#define DK 64

typedef __attribute__((ext_vector_type(8))) short short8;
typedef __attribute__((ext_vector_type(4))) float f32x4;

__device__ inline unsigned short f2bf(float f) {
  unsigned int u = __builtin_bit_cast(unsigned int, f);
  unsigned int r = (u + 0x7fffu + ((u >> 16) & 1u)) >> 16;
  return (unsigned short)r;
}

#define GLOAD_LDS16(g, l) \
  __builtin_amdgcn_global_load_lds((const __attribute__((address_space(1))) unsigned int*)(g), \
      (__attribute__((address_space(3))) unsigned int*)(l), 16, 0, 0)

// ---------------- f32 -> bf16 convert ----------------
__global__ void cvt_kernel(const float* __restrict__ in, unsigned short* __restrict__ out, int n) {
  int i = (blockIdx.x * 256 + threadIdx.x) * 8;
  if (i >= n) return;
  const float4* p = (const float4*)(in + i);
  float4 a = p[0], b = p[1];
  union { unsigned short u[8]; uint4 v; } r;
  r.u[0] = f2bf(a.x); r.u[1] = f2bf(a.y); r.u[2] = f2bf(a.z); r.u[3] = f2bf(a.w);
  r.u[4] = f2bf(b.x); r.u[5] = f2bf(b.y); r.u[6] = f2bf(b.z); r.u[7] = f2bf(b.w);
  *(uint4*)(out + i) = r.v;
}

// ---------------- GEMM: C[M,N] = A[M,K] * B[N,K]^T + bias ----------------
// A, B bf16 row-major. CT = unsigned short (bf16 out) or float.
template <typename CT>
__global__ __launch_bounds__(256)
void gemm_bt(const unsigned short* __restrict__ A, const unsigned short* __restrict__ B,
             const float* __restrict__ bias, CT* __restrict__ C, int M, int N, int K) {
  __shared__ unsigned short As[128 * 64];
  __shared__ unsigned short Bs[128 * 64];
  const int t = threadIdx.x;
  const int l = t & 63;
  const int w = t >> 6;
  const int wr = w >> 1, wc = w & 1;
  const int l15 = l & 15, lg = l >> 4;
  const int m0 = blockIdx.y * 128, n0 = blockIdx.x * 128;

  f32x4 acc[4][4] = {};

  const int srow = t >> 3;       // 0..31
  const int scol = (t & 7) * 8;  // 0..56

  for (int k0 = 0; k0 < K; k0 += 64) {
    #pragma unroll
    for (int i = 0; i < 4; ++i) {
      GLOAD_LDS16(A + (size_t)(m0 + i * 32 + srow) * K + k0 + scol, &As[(i * 32 + srow) * 64 + scol]);
      GLOAD_LDS16(B + (size_t)(n0 + i * 32 + srow) * K + k0 + scol, &Bs[(i * 32 + srow) * 64 + scol]);
    }
    __syncthreads();
    #pragma unroll
    for (int kk = 0; kk < 2; ++kk) {
      short8 af[4], bfr[4];
      #pragma unroll
      for (int m = 0; m < 4; ++m)
        af[m] = *(const short8*)&As[(wr * 64 + m * 16 + l15) * 64 + kk * 32 + lg * 8];
      #pragma unroll
      for (int n = 0; n < 4; ++n)
        bfr[n] = *(const short8*)&Bs[(wc * 64 + n * 16 + l15) * 64 + kk * 32 + lg * 8];
      #pragma unroll
      for (int m = 0; m < 4; ++m)
        #pragma unroll
        for (int n = 0; n < 4; ++n)
          acc[m][n] = __builtin_amdgcn_mfma_f32_16x16x32_bf16(af[m], bfr[n], acc[m][n], 0, 0, 0);
    }
    __syncthreads();
  }

  #pragma unroll
  for (int m = 0; m < 4; ++m) {
    #pragma unroll
    for (int n = 0; n < 4; ++n) {
      int col = n0 + wc * 64 + n * 16 + l15;
      float bz = bias[col];
      #pragma unroll
      for (int r = 0; r < 4; ++r) {
        int row = m0 + wr * 64 + m * 16 + lg * 4 + r;
        float v = acc[m][n][r] + bz;
        if constexpr (sizeof(CT) == 2) {
          C[(size_t)row * N + col] = (CT)f2bf(v);
        } else {
          C[(size_t)row * N + col] = v;
        }
      }
    }
  }
}

// ---------------- causal flash attention ----------------
// Q,K,V: [B*S, D_MODEL] bf16, head h occupies cols h*64..h*64+63. AO same layout.
__global__ __launch_bounds__(256)
void attn_kernel(const unsigned short* __restrict__ Q, const unsigned short* __restrict__ K,
                 const unsigned short* __restrict__ V, unsigned short* __restrict__ AO) {
  __shared__ unsigned short Ks[64 * 64];
  __shared__ unsigned short Vt[64 * 72];
  __shared__ unsigned short Pl[4][16][72];

  const int t = threadIdx.x;
  const int l = t & 63;
  const int w = t >> 6;
  const int l15 = l & 15, lg = l >> 4;
  const int qt = blockIdx.x;  // q tile, 0..31
  const int bh = blockIdx.y;  // 0..63
  const int b = bh >> 4, h = bh & 15;

  const size_t headoff = (size_t)b * SEQ * D_MODEL + (size_t)h * DK;

  // Q fragments for this wave's 16 q-rows (hoisted)
  short8 qf[2];
  {
    int qrow = qt * 64 + w * 16 + l15;
    const unsigned short* qp = Q + headoff + (size_t)qrow * D_MODEL + lg * 8;
    qf[0] = *(const short8*)qp;
    qf[1] = *(const short8*)(qp + 32);
  }

  f32x4 o[4] = {};
  float mrow[4] = {-INFINITY, -INFINITY, -INFINITY, -INFINITY};
  float lrow[4] = {0.f, 0.f, 0.f, 0.f};

  const int srow = t >> 3, scol = (t & 7) * 8;
  const int vkv = t & 63, vdk = (t >> 6) * 16;

  for (int kvt = 0; kvt <= qt; ++kvt) {
    const int kv0 = kvt * 64;
    // stage K tile [64 kv][64 dk] linear
    GLOAD_LDS16(K + headoff + (size_t)(kv0 + srow) * D_MODEL + scol, &Ks[srow * 64 + scol]);
    GLOAD_LDS16(K + headoff + (size_t)(kv0 + 32 + srow) * D_MODEL + scol, &Ks[(32 + srow) * 64 + scol]);
    // stage V transposed: Vt[dk][kv]
    {
      const unsigned short* vp = V + headoff + (size_t)(kv0 + vkv) * D_MODEL + vdk;
      short8 v0 = *(const short8*)vp;
      short8 v1 = *(const short8*)(vp + 8);
      #pragma unroll
      for (int j = 0; j < 8; ++j) Vt[(vdk + j) * 72 + vkv] = (unsigned short)v0[j];
      #pragma unroll
      for (int j = 0; j < 8; ++j) Vt[(vdk + 8 + j) * 72 + vkv] = (unsigned short)v1[j];
    }
    __syncthreads();

    // S = Q * K^T  (16 q-rows x 64 kv)
    f32x4 s[4];
    #pragma unroll
    for (int n = 0; n < 4; ++n) {
      f32x4 z = {};
      #pragma unroll
      for (int ks = 0; ks < 2; ++ks) {
        short8 kf = *(const short8*)&Ks[(n * 16 + l15) * 64 + ks * 32 + lg * 8];
        z = __builtin_amdgcn_mfma_f32_16x16x32_bf16(qf[ks], kf, z, 0, 0, 0);
      }
      s[n] = z;
    }

    // scale + causal mask + row max
    float pm[4] = {-INFINITY, -INFINITY, -INFINITY, -INFINITY};
    #pragma unroll
    for (int n = 0; n < 4; ++n) {
      int kv = kv0 + n * 16 + l15;
      #pragma unroll
      for (int r = 0; r < 4; ++r) {
        int qrow = qt * 64 + w * 16 + lg * 4 + r;
        float v = s[n][r] * 0.125f;
        v = (kv <= qrow) ? v : -INFINITY;
        s[n][r] = v;
        pm[r] = fmaxf(pm[r], v);
      }
    }
    #pragma unroll
    for (int mask = 1; mask < 16; mask <<= 1)
      #pragma unroll
      for (int r = 0; r < 4; ++r)
        pm[r] = fmaxf(pm[r], __shfl_xor(pm[r], mask, 64));

    float al[4], psum[4];
    #pragma unroll
    for (int r = 0; r < 4; ++r) {
      float mn = fmaxf(mrow[r], pm[r]);
      al[r] = __expf(mrow[r] - mn);
      mrow[r] = mn;
      psum[r] = 0.f;
    }

    // P = exp(s - m); write to per-wave LDS for layout transpose
    #pragma unroll
    for (int n = 0; n < 4; ++n) {
      #pragma unroll
      for (int r = 0; r < 4; ++r) {
        float p = __expf(s[n][r] - mrow[r]);
        psum[r] += p;
        Pl[w][lg * 4 + r][n * 16 + l15] = f2bf(p);
      }
    }
    #pragma unroll
    for (int mask = 1; mask < 16; mask <<= 1)
      #pragma unroll
      for (int r = 0; r < 4; ++r)
        psum[r] += __shfl_xor(psum[r], mask, 64);
    #pragma unroll
    for (int r = 0; r < 4; ++r) lrow[r] = lrow[r] * al[r] + psum[r];

    // rescale O
    #pragma unroll
    for (int n = 0; n < 4; ++n)
      #pragma unroll
      for (int r = 0; r < 4; ++r)
        o[n][r] *= al[r];

    // PV: O += P * V
    short8 pa[2];
    pa[0] = *(const short8*)&Pl[w][l15][lg * 8];
    pa[1] = *(const short8*)&Pl[w][l15][32 + lg * 8];
    #pragma unroll
    for (int n = 0; n < 4; ++n) {
      #pragma unroll
      for (int ks = 0; ks < 2; ++ks) {
        short8 vf = *(const short8*)&Vt[(n * 16 + l15) * 72 + ks * 32 + lg * 8];
        o[n] = __builtin_amdgcn_mfma_f32_16x16x32_bf16(pa[ks], vf, o[n], 0, 0, 0);
      }
    }
    __syncthreads();
  }

  // write normalized output
  #pragma unroll
  for (int r = 0; r < 4; ++r) {
    int qrow = qt * 64 + w * 16 + lg * 4 + r;
    float inv = 1.f / lrow[r];
    unsigned short* op = AO + headoff + (size_t)qrow * D_MODEL;
    #pragma unroll
    for (int n = 0; n < 4; ++n)
      op[n * 16 + l15] = f2bf(o[n][r] * inv);
  }
}

extern "C" void kernel_launch(void* const* d_in, const int* in_sizes, int n_in,
                              void* d_out, int out_size, void* d_ws, size_t ws_size,
                              hipStream_t stream) {
  const float* x   = (const float*)d_in[0];
  const float* WQw = (const float*)d_in[1];
  const float* WQb = (const float*)d_in[2];
  const float* WKw = (const float*)d_in[3];
  const float* WKb = (const float*)d_in[4];
  const float* WVw = (const float*)d_in[5];
  const float* WVb = (const float*)d_in[6];
  const float* WOw = (const float*)d_in[7];
  const float* WOb = (const float*)d_in[8];
  float* out = (float*)d_out;

  const int M = BATCH * SEQ;       // 8192
  const int D = D_MODEL;           // 1024
  const int NX = M * D;            // 8388608
  const int NW = D * D;            // 1048576

  unsigned short* xb = (unsigned short*)d_ws;
  unsigned short* wq = xb + NX;
  unsigned short* wk = wq + NW;
  unsigned short* wv = wk + NW;
  unsigned short* wo = wv + NW;
  unsigned short* Qb = wo + NW;
  unsigned short* Kb = Qb + NX;
  unsigned short* Vb = Kb + NX;
  unsigned short* AOb = xb;  // reuse x-bf16 region after QKV projections

  cvt_kernel<<<NX / 8 / 256, 256, 0, stream>>>(x, xb, NX);
  cvt_kernel<<<NW / 8 / 256, 256, 0, stream>>>(WQw, wq, NW);
  cvt_kernel<<<NW / 8 / 256, 256, 0, stream>>>(WKw, wk, NW);
  cvt_kernel<<<NW / 8 / 256, 256, 0, stream>>>(WVw, wv, NW);
  cvt_kernel<<<NW / 8 / 256, 256, 0, stream>>>(WOw, wo, NW);

  dim3 gg(D / 128, M / 128);  // (8, 64)
  gemm_bt<unsigned short><<<gg, 256, 0, stream>>>(xb, wq, WQb, Qb, M, D, D);
  gemm_bt<unsigned short><<<gg, 256, 0, stream>>>(xb, wk, WKb, Kb, M, D, D);
  gemm_bt<unsigned short><<<gg, 256, 0, stream>>>(xb, wv, WVb, Vb, M, D, D);

  attn_kernel<<<dim3(SEQ / 64, BATCH * NHEAD), 256, 0, stream>>>(Qb, Kb, Vb, AOb);

  gemm_bt<float><<<gg, 256, 0, stream>>>(AOb, wo, WOb, out, M, D, D);
}

// Round 2
// 270.094 us; speedup vs baseline: 1.4793x; 1.4793x over previous
//
#include <hip/hip_runtime.h>
#include <hip/hip_bf16.h>
#include <stdint.h>

#define D_MODEL 1024
#define NHEAD 16
#define SEQ 2048
#define BATCH 4
#define DK 64

typedef __attribute__((ext_vector_type(8))) short short8;
typedef __attribute__((ext_vector_type(4))) float f32x4;

#if __has_builtin(__builtin_amdgcn_exp2f)
#define EXP2(x) __builtin_amdgcn_exp2f(x)
#else
#define EXP2(x) exp2f(x)
#endif

__device__ inline unsigned short f2bf(float f) {
  unsigned int u = __builtin_bit_cast(unsigned int, f);
  unsigned int r = (u + 0x7fffu + ((u >> 16) & 1u)) >> 16;
  return (unsigned short)r;
}

#define GLOAD_LDS16(g, l) \
  __builtin_amdgcn_global_load_lds((const __attribute__((address_space(1))) unsigned int*)(g), \
      (__attribute__((address_space(3))) unsigned int*)(l), 16, 0, 0)

// ---------------- f32 -> bf16 convert ----------------
__global__ void cvt_kernel(const float* __restrict__ in, unsigned short* __restrict__ out, int n) {
  int i = (blockIdx.x * 256 + threadIdx.x) * 8;
  if (i >= n) return;
  const float4* p = (const float4*)(in + i);
  float4 a = p[0], b = p[1];
  union { unsigned short u[8]; uint4 v; } r;
  r.u[0] = f2bf(a.x); r.u[1] = f2bf(a.y); r.u[2] = f2bf(a.z); r.u[3] = f2bf(a.w);
  r.u[4] = f2bf(b.x); r.u[5] = f2bf(b.y); r.u[6] = f2bf(b.z); r.u[7] = f2bf(b.w);
  *(uint4*)(out + i) = r.v;
}

// ---------------- GEMM: C[M,N] = alpha*(A[M,K] * B[N,K]^T + bias) ----------------
template <typename CT>
__global__ __launch_bounds__(256)
void gemm_bt(const unsigned short* __restrict__ A, const unsigned short* __restrict__ B,
             const float* __restrict__ bias, CT* __restrict__ C, int M, int N, int K,
             float alpha) {
  __shared__ unsigned short As[128 * 64];
  __shared__ unsigned short Bs[128 * 64];
  const int t = threadIdx.x;
  const int l = t & 63;
  const int w = t >> 6;
  const int wr = w >> 1, wc = w & 1;
  const int l15 = l & 15, lg = l >> 4;
  const int m0 = blockIdx.y * 128, n0 = blockIdx.x * 128;

  f32x4 acc[4][4] = {};

  const int srow = t >> 3;       // 0..31
  const int scol = (t & 7) * 8;  // 0..56

  for (int k0 = 0; k0 < K; k0 += 64) {
    #pragma unroll
    for (int i = 0; i < 4; ++i) {
      GLOAD_LDS16(A + (size_t)(m0 + i * 32 + srow) * K + k0 + scol, &As[(i * 32 + srow) * 64 + scol]);
      GLOAD_LDS16(B + (size_t)(n0 + i * 32 + srow) * K + k0 + scol, &Bs[(i * 32 + srow) * 64 + scol]);
    }
    __syncthreads();
    #pragma unroll
    for (int kk = 0; kk < 2; ++kk) {
      short8 af[4], bfr[4];
      #pragma unroll
      for (int m = 0; m < 4; ++m)
        af[m] = *(const short8*)&As[(wr * 64 + m * 16 + l15) * 64 + kk * 32 + lg * 8];
      #pragma unroll
      for (int n = 0; n < 4; ++n)
        bfr[n] = *(const short8*)&Bs[(wc * 64 + n * 16 + l15) * 64 + kk * 32 + lg * 8];
      #pragma unroll
      for (int m = 0; m < 4; ++m)
        #pragma unroll
        for (int n = 0; n < 4; ++n)
          acc[m][n] = __builtin_amdgcn_mfma_f32_16x16x32_bf16(af[m], bfr[n], acc[m][n], 0, 0, 0);
    }
    __syncthreads();
  }

  #pragma unroll
  for (int m = 0; m < 4; ++m) {
    #pragma unroll
    for (int n = 0; n < 4; ++n) {
      int col = n0 + wc * 64 + n * 16 + l15;
      float bz = bias[col];
      #pragma unroll
      for (int r = 0; r < 4; ++r) {
        int row = m0 + wr * 64 + m * 16 + lg * 4 + r;
        float v = (acc[m][n][r] + bz) * alpha;
        if constexpr (sizeof(CT) == 2) {
          C[(size_t)row * N + col] = (CT)f2bf(v);
        } else {
          C[(size_t)row * N + col] = v;
        }
      }
    }
  }
}

// ---------------- causal flash attention, paired q-tiles ----------------
// Q pre-scaled by 0.125*log2(e); softmax done in exp2 domain.
// Block i handles q-tiles {31-i, i} so every block does exactly 33 qtile-units.
__global__ __launch_bounds__(256, 4)
void attn_kernel(const unsigned short* __restrict__ Q, const unsigned short* __restrict__ K,
                 const unsigned short* __restrict__ V, unsigned short* __restrict__ AO) {
  __shared__ unsigned short Ks[64 * 64];
  __shared__ unsigned short Vt[64 * 72];
  __shared__ unsigned short Pl[4][16][72];

  const int t = threadIdx.x;
  const int l = t & 63;
  const int w = t >> 6;
  const int l15 = l & 15, lg = l >> 4;
  const int i = blockIdx.x;     // 0..15
  const int qtA = 31 - i;       // long q-tile
  const int qtB = i;            // short q-tile
  const int bh = blockIdx.y;
  const int b = bh >> 4, h = bh & 15;
  const size_t headoff = (size_t)b * SEQ * D_MODEL + (size_t)h * DK;

  // hoisted Q fragments for both q-tiles
  short8 qfA[2], qfB[2];
  {
    const unsigned short* qp = Q + headoff + (size_t)(qtA * 64 + w * 16 + l15) * D_MODEL + lg * 8;
    qfA[0] = *(const short8*)qp; qfA[1] = *(const short8*)(qp + 32);
    qp = Q + headoff + (size_t)(qtB * 64 + w * 16 + l15) * D_MODEL + lg * 8;
    qfB[0] = *(const short8*)qp; qfB[1] = *(const short8*)(qp + 32);
  }

  f32x4 oA[4] = {}, oB[4] = {};
  float mA[4], lA[4], mB[4], lB[4];
  #pragma unroll
  for (int r = 0; r < 4; ++r) { mA[r] = -INFINITY; lA[r] = 0.f; mB[r] = -INFINITY; lB[r] = 0.f; }

  const int srow = t >> 3, sc8 = t & 7;
  const int kssw = sc8 ^ (srow & 7);      // XOR-swizzled global source slot
  const int vkv = t & 63, vdk = (t >> 6) * 16;
  const int qrowbase = w * 16 + lg * 4;   // + qt*64 + r gives absolute q row

  // softmax update: consumes s (exp2-domain scores), updates (m, lr, o), leaves P in Pl, reads pa
  auto softmax_upd = [&](f32x4 (&s)[4], float (&m)[4], float (&lr)[4], f32x4 (&o)[4],
                         bool diag, int qt, int kv0, short8 (&pa)[2]) {
    if (diag) {
      #pragma unroll
      for (int n = 0; n < 4; ++n) {
        int kv = kv0 + n * 16 + l15;
        #pragma unroll
        for (int r = 0; r < 4; ++r) {
          int qrow = qt * 64 + qrowbase + r;
          if (kv > qrow) s[n][r] = -INFINITY;
        }
      }
    }
    float pm[4] = {-INFINITY, -INFINITY, -INFINITY, -INFINITY};
    #pragma unroll
    for (int n = 0; n < 4; ++n)
      #pragma unroll
      for (int r = 0; r < 4; ++r) pm[r] = fmaxf(pm[r], s[n][r]);
    #pragma unroll
    for (int mask = 1; mask < 16; mask <<= 1)
      #pragma unroll
      for (int r = 0; r < 4; ++r) pm[r] = fmaxf(pm[r], __shfl_xor(pm[r], mask, 64));
    float al[4], ps[4];
    #pragma unroll
    for (int r = 0; r < 4; ++r) {
      float mn = fmaxf(m[r], pm[r]);
      al[r] = EXP2(m[r] - mn);
      m[r] = mn; ps[r] = 0.f;
    }
    #pragma unroll
    for (int n = 0; n < 4; ++n)
      #pragma unroll
      for (int r = 0; r < 4; ++r) {
        float p = EXP2(s[n][r] - m[r]);
        ps[r] += p;
        Pl[w][lg * 4 + r][n * 16 + l15] = f2bf(p);
      }
    #pragma unroll
    for (int mask = 1; mask < 16; mask <<= 1)
      #pragma unroll
      for (int r = 0; r < 4; ++r) ps[r] += __shfl_xor(ps[r], mask, 64);
    #pragma unroll
    for (int r = 0; r < 4; ++r) lr[r] = lr[r] * al[r] + ps[r];
    #pragma unroll
    for (int n = 0; n < 4; ++n)
      #pragma unroll
      for (int r = 0; r < 4; ++r) o[n][r] *= al[r];
    pa[0] = *(const short8*)&Pl[w][l15][lg * 8];
    pa[1] = *(const short8*)&Pl[w][l15][32 + lg * 8];
  };

  const int ntiles = qtA + 1;
  for (int kvt = 0; kvt < ntiles; ++kvt) {
    const int kv0 = kvt * 64;
    // stage K: swizzled global source, linear LDS dest (dest = wave base + lane*16)
    GLOAD_LDS16(K + headoff + (size_t)(kv0 + srow) * D_MODEL + kssw * 8, &Ks[srow * 64 + sc8 * 8]);
    GLOAD_LDS16(K + headoff + (size_t)(kv0 + 32 + srow) * D_MODEL + kssw * 8, &Ks[(32 + srow) * 64 + sc8 * 8]);
    // stage V transposed: Vt[dk][kv]
    {
      const unsigned short* vp = V + headoff + (size_t)(kv0 + vkv) * D_MODEL + vdk;
      short8 v0 = *(const short8*)vp;
      short8 v1 = *(const short8*)(vp + 8);
      #pragma unroll
      for (int j = 0; j < 8; ++j) Vt[(vdk + j) * 72 + vkv] = (unsigned short)v0[j];
      #pragma unroll
      for (int j = 0; j < 8; ++j) Vt[(vdk + 8 + j) * 72 + vkv] = (unsigned short)v1[j];
    }
    __syncthreads();

    const bool bAct = (kvt <= qtB);
    short8 paA[2], paB[2];

    // ---- QK^T + softmax, q-tile A ----
    {
      f32x4 s[4];
      #pragma unroll
      for (int n = 0; n < 4; ++n) {
        int row = n * 16 + l15;
        short8 kf0 = *(const short8*)&Ks[row * 64 + ((lg ^ (row & 7)) * 8)];
        short8 kf1 = *(const short8*)&Ks[row * 64 + (((4 + lg) ^ (row & 7)) * 8)];
        f32x4 z = {};
        z = __builtin_amdgcn_mfma_f32_16x16x32_bf16(qfA[0], kf0, z, 0, 0, 0);
        z = __builtin_amdgcn_mfma_f32_16x16x32_bf16(qfA[1], kf1, z, 0, 0, 0);
        s[n] = z;
      }
      softmax_upd(s, mA, lA, oA, kvt == qtA, qtA, kv0, paA);
    }
    // ---- QK^T + softmax, q-tile B ----
    if (bAct) {
      f32x4 s[4];
      #pragma unroll
      for (int n = 0; n < 4; ++n) {
        int row = n * 16 + l15;
        short8 kf0 = *(const short8*)&Ks[row * 64 + ((lg ^ (row & 7)) * 8)];
        short8 kf1 = *(const short8*)&Ks[row * 64 + (((4 + lg) ^ (row & 7)) * 8)];
        f32x4 z = {};
        z = __builtin_amdgcn_mfma_f32_16x16x32_bf16(qfB[0], kf0, z, 0, 0, 0);
        z = __builtin_amdgcn_mfma_f32_16x16x32_bf16(qfB[1], kf1, z, 0, 0, 0);
        s[n] = z;
      }
      softmax_upd(s, mB, lB, oB, kvt == qtB, qtB, kv0, paB);
    }

    // ---- PV for both q-tiles, shared V fragments ----
    #pragma unroll
    for (int n = 0; n < 4; ++n) {
      int row = n * 16 + l15;
      short8 vf0 = *(const short8*)&Vt[row * 72 + lg * 8];
      short8 vf1 = *(const short8*)&Vt[row * 72 + 32 + lg * 8];
      oA[n] = __builtin_amdgcn_mfma_f32_16x16x32_bf16(paA[0], vf0, oA[n], 0, 0, 0);
      oA[n] = __builtin_amdgcn_mfma_f32_16x16x32_bf16(paA[1], vf1, oA[n], 0, 0, 0);
      if (bAct) {
        oB[n] = __builtin_amdgcn_mfma_f32_16x16x32_bf16(paB[0], vf0, oB[n], 0, 0, 0);
        oB[n] = __builtin_amdgcn_mfma_f32_16x16x32_bf16(paB[1], vf1, oB[n], 0, 0, 0);
      }
    }
    __syncthreads();
  }

  // write normalized outputs for both q-tiles
  #pragma unroll
  for (int r = 0; r < 4; ++r) {
    float invA = 1.f / lA[r];
    unsigned short* opA = AO + headoff + (size_t)(qtA * 64 + qrowbase + r) * D_MODEL;
    #pragma unroll
    for (int n = 0; n < 4; ++n) opA[n * 16 + l15] = f2bf(oA[n][r] * invA);
    float invB = 1.f / lB[r];
    unsigned short* opB = AO + headoff + (size_t)(qtB * 64 + qrowbase + r) * D_MODEL;
    #pragma unroll
    for (int n = 0; n < 4; ++n) opB[n * 16 + l15] = f2bf(oB[n][r] * invB);
  }
}

extern "C" void kernel_launch(void* const* d_in, const int* in_sizes, int n_in,
                              void* d_out, int out_size, void* d_ws, size_t ws_size,
                              hipStream_t stream) {
  const float* x   = (const float*)d_in[0];
  const float* WQw = (const float*)d_in[1];
  const float* WQb = (const float*)d_in[2];
  const float* WKw = (const float*)d_in[3];
  const float* WKb = (const float*)d_in[4];
  const float* WVw = (const float*)d_in[5];
  const float* WVb = (const float*)d_in[6];
  const float* WOw = (const float*)d_in[7];
  const float* WOb = (const float*)d_in[8];
  float* out = (float*)d_out;

  const int M = BATCH * SEQ;       // 8192
  const int D = D_MODEL;           // 1024
  const int NX = M * D;            // 8388608
  const int NW = D * D;            // 1048576

  unsigned short* xb = (unsigned short*)d_ws;
  unsigned short* wq = xb + NX;
  unsigned short* wk = wq + NW;
  unsigned short* wv = wk + NW;
  unsigned short* wo = wv + NW;
  unsigned short* Qb = wo + NW;
  unsigned short* Kb = Qb + NX;
  unsigned short* Vb = Kb + NX;
  unsigned short* AOb = xb;  // reuse x-bf16 region after QKV projections

  cvt_kernel<<<NX / 8 / 256, 256, 0, stream>>>(x, xb, NX);
  cvt_kernel<<<NW / 8 / 256, 256, 0, stream>>>(WQw, wq, NW);
  cvt_kernel<<<NW / 8 / 256, 256, 0, stream>>>(WKw, wk, NW);
  cvt_kernel<<<NW / 8 / 256, 256, 0, stream>>>(WVw, wv, NW);
  cvt_kernel<<<NW / 8 / 256, 256, 0, stream>>>(WOw, wo, NW);

  dim3 gg(D / 128, M / 128);  // (8, 64)
  const float qscale = 0.125f * 1.4426950408889634f;  // fold softmax scale + log2(e) into Q
  gemm_bt<unsigned short><<<gg, 256, 0, stream>>>(xb, wq, WQb, Qb, M, D, D, qscale);
  gemm_bt<unsigned short><<<gg, 256, 0, stream>>>(xb, wk, WKb, Kb, M, D, D, 1.0f);
  gemm_bt<unsigned short><<<gg, 256, 0, stream>>>(xb, wv, WVb, Vb, M, D, D, 1.0f);

  attn_kernel<<<dim3(16, BATCH * NHEAD), 256, 0, stream>>>(Qb, Kb, Vb, AOb);

  gemm_bt<float><<<gg, 256, 0, stream>>>(AOb, wo, WOb, out, M, D, D, 1.0f);
}